// Round 1
// baseline (4220.443 us; speedup 1.0000x reference)
//
#include <hip/hip_runtime.h>
#include <hip/hip_bf16.h>

#define BB 64
#define TT 64
#define FF 256
#define CC 64
#define KK 9
#define GG 256   // 4*C
#define TF 32    // f-positions per block
#define ROWS (TF + 8)    // 40 (with halo of 4 each side)
#define HSTRIDE 44       // padded LDS row stride (44*4=176 B, 16B aligned)

__device__ __forceinline__ float sigmoidf_(float x) {
    return 1.0f / (1.0f + __expf(-x));
}

__global__ __launch_bounds__(256) void convlstm_step(
    const float* __restrict__ z,     // (B,T,F,1)
    const float* __restrict__ h_in,  // (B,F,C)
    const float* __restrict__ c_in,  // (B,F,C)
    const float* __restrict__ Wx,    // (K,1,4C)
    const float* __restrict__ Wh,    // (K,C,4C)
    const float* __restrict__ bias,  // (4C)
    float* __restrict__ h_out,       // (B,F,C)
    float* __restrict__ c_out,       // (B,F,C)
    float* __restrict__ out,         // (B, T*F)
    int t)
{
    __shared__ __align__(16) float hT[CC][HSTRIDE];  // transposed h tile [cin][frow]
    __shared__ float zrow[ROWS];
    __shared__ __align__(16) float gates[TF][GG];    // 32 KB

    const int b = blockIdx.x;
    const int f0 = blockIdx.y * TF;
    const int tid = threadIdx.x;

    // ---- stage h tile (transposed) and z row into LDS, zero-padded at edges
    for (int idx = tid; idx < ROWS * CC; idx += 256) {
        const int fr = idx >> 6;        // 0..39
        const int cin = idx & 63;
        const int f = f0 - 4 + fr;
        float v = 0.0f;
        if (f >= 0 && f < FF) v = h_in[(b * FF + f) * CC + cin];
        hT[cin][fr] = v;
    }
    if (tid < ROWS) {
        const int f = f0 - 4 + tid;
        float v = 0.0f;
        if (f >= 0 && f < FF) v = z[(b * TT + t) * FF + f];
        zrow[tid] = v;
    }
    __syncthreads();

    // ---- each thread owns one gate column g = tid, computes TF outputs
    const int g = tid;
    float acc[TF];
    {
        const float bv = bias[g];
        float wx[KK];
        #pragma unroll
        for (int k = 0; k < KK; ++k) wx[k] = Wx[k * GG + g];
        #pragma unroll
        for (int f = 0; f < TF; ++f) {
            float a = bv;
            #pragma unroll
            for (int k = 0; k < KK; ++k) a += zrow[f + k] * wx[k];
            acc[f] = a;
        }
    }

    // ---- main GEMM loop: gates[f][g] += sum_{k,cin} h[f+k-4][cin] * Wh[k][cin][g]
    for (int cin = 0; cin < CC; ++cin) {
        float row[ROWS];
        #pragma unroll
        for (int q = 0; q < ROWS / 4; ++q) {
            const float4 v = *reinterpret_cast<const float4*>(&hT[cin][q * 4]);
            row[q * 4 + 0] = v.x; row[q * 4 + 1] = v.y;
            row[q * 4 + 2] = v.z; row[q * 4 + 3] = v.w;
        }
        #pragma unroll
        for (int k = 0; k < KK; ++k) {
            const float w = Wh[(k * CC + cin) * GG + g];
            #pragma unroll
            for (int f = 0; f < TF; ++f)
                acc[f] = fmaf(row[f + k], w, acc[f]);
        }
    }

    #pragma unroll
    for (int f = 0; f < TF; ++f) gates[f][g] = acc[f];
    __syncthreads();

    // ---- LSTM cell update + per-f mean. thread -> (f_local = tid>>3, 8 channels)
    const int fl = tid >> 3;             // 0..31
    const int ch0 = (tid & 7) * 8;       // 0,8,...,56
    const int f = f0 + fl;
    const long base = (long)(b * FF + f) * CC + ch0;

    float hsum = 0.0f;
    float hv[8], cv[8];
    #pragma unroll
    for (int j = 0; j < 8; ++j) {
        const int ch = ch0 + j;
        const float gi = gates[fl][ch];
        const float gj = gates[fl][64 + ch];
        const float gf = gates[fl][128 + ch];
        const float go = gates[fl][192 + ch];
        const float cold = c_in[base + j];
        const float cnew = cold * sigmoidf_(gf + 1.0f) + sigmoidf_(gi) * tanhf(gj);
        const float hnew = tanhf(cnew) * sigmoidf_(go);
        cv[j] = cnew;
        hv[j] = hnew;
        hsum += hnew;
    }
    #pragma unroll
    for (int j = 0; j < 8; j += 4) {
        *reinterpret_cast<float4*>(&c_out[base + j]) = make_float4(cv[j], cv[j+1], cv[j+2], cv[j+3]);
        *reinterpret_cast<float4*>(&h_out[base + j]) = make_float4(hv[j], hv[j+1], hv[j+2], hv[j+3]);
    }

    // reduce hsum across the 8 lanes sharing this f (consecutive lanes)
    hsum += __shfl_down(hsum, 4, 8);
    hsum += __shfl_down(hsum, 2, 8);
    hsum += __shfl_down(hsum, 1, 8);
    if ((tid & 7) == 0)
        out[(long)b * (TT * FF) + t * FF + f] = tanhf(hsum * (1.0f / 64.0f));
}

extern "C" void kernel_launch(void* const* d_in, const int* in_sizes, int n_in,
                              void* d_out, int out_size, void* d_ws, size_t ws_size,
                              hipStream_t stream) {
    const float* z    = (const float*)d_in[0];
    const float* h0   = (const float*)d_in[1];
    const float* c0   = (const float*)d_in[2];
    const float* Wx   = (const float*)d_in[3];
    const float* Wh   = (const float*)d_in[4];
    const float* bias = (const float*)d_in[5];
    float* out = (float*)d_out;

    const int state_elems = BB * FF * CC;  // 1,048,576
    float* hA = (float*)d_ws;
    float* hB = hA + state_elems;
    float* cW = hA + 2 * state_elems;

    dim3 grid(BB, FF / TF);  // 64 x 8 = 512 blocks
    for (int t = 0; t < TT; ++t) {
        const float* hin = (t == 0) ? h0 : ((t & 1) ? hA : hB);
        float* hout = (t & 1) ? hB : hA;
        const float* cin = (t == 0) ? c0 : cW;
        convlstm_step<<<grid, 256, 0, stream>>>(z, hin, cin, Wx, Wh, bias,
                                                hout, cW, out, t);
    }
}

// Round 3
// 1522.874 us; speedup vs baseline: 2.7714x; 2.7714x over previous
//
#include <hip/hip_runtime.h>
#include <hip/hip_bf16.h>

#define BB 64
#define TT 64
#define FF 256
#define CC 64
#define GG 256   // 4*C
#define GST 268  // gates LDS row stride (floats), padded for bank spread

using frag_ab = __attribute__((ext_vector_type(8))) short;  // 8 bf16
using f32x4   = __attribute__((ext_vector_type(4))) float;

__device__ __forceinline__ float sigmoidf_(float x) {
    return 1.0f / (1.0f + __expf(-x));
}

__device__ __forceinline__ void split2(float v, short* hi, short* lo) {
    __hip_bfloat16 h = __float2bfloat16(v);
    __hip_bfloat16 l = __float2bfloat16(v - __bfloat162float(h));
    *hi = *reinterpret_cast<short*>(&h);
    *lo = *reinterpret_cast<short*>(&l);
}

// ---- prep: split Wh -> (hi,lo) in [k][g][cin] layout, Wx -> [g][32] hi/lo, h0 -> hi/lo
__global__ __launch_bounds__(256) void prep_kernel(
    const float* __restrict__ Wh, const float* __restrict__ Wx,
    const float* __restrict__ h0,
    short* __restrict__ WhTh, short* __restrict__ WhTl,
    short* __restrict__ WxTh, short* __restrict__ WxTl,
    short* __restrict__ h0h, short* __restrict__ h0l)
{
    const int n = blockIdx.x * 256 + threadIdx.x;
    if (n < BB * FF * CC) split2(h0[n], &h0h[n], &h0l[n]);
    if (n < 9 * GG * CC) {
        const int cin = n & 63;
        const int g = (n >> 6) & 255;
        const int k = n >> 14;
        split2(Wh[(k * CC + cin) * GG + g], &WhTh[n], &WhTl[n]);
    }
    if (n < GG * 32) {
        const int kz = n & 31;
        const int g = n >> 5;
        split2(kz < 9 ? Wx[kz * GG + g] : 0.0f, &WxTh[n], &WxTl[n]);
    }
}

__global__ __launch_bounds__(512) void convlstm_step(
    const float* __restrict__ z,
    const short* __restrict__ hinh, const short* __restrict__ hinl,
    const float* __restrict__ c_in,
    const short* __restrict__ WhTh, const short* __restrict__ WhTl,
    const short* __restrict__ WxTh, const short* __restrict__ WxTl,
    const float* __restrict__ bias,
    short* __restrict__ houth, short* __restrict__ houtl,
    float* __restrict__ c_out,
    float* __restrict__ out, int t)
{
    __shared__ __align__(16) char hbyh[72 * 128];   // h hi tile, swizzled
    __shared__ __align__(16) char hbyl[72 * 128];   // h lo tile
    __shared__ __align__(16) char zbyh[64 * 64];    // z hi tile
    __shared__ __align__(16) char zbyl[64 * 64];    // z lo tile
    __shared__ __align__(16) float gbuf[64 * GST];  // gates fp32

    const int b = blockIdx.x;
    const int f0 = blockIdx.y * 64;
    const int tid = threadIdx.x;
    const int lane = tid & 63;
    const int w = tid >> 6;          // 0..7 : 32-col slice owner

    // ---- stage h tile rows f0-4 .. f0+67 (hi+lo), XOR-swizzled 16B slots
    for (int idx = tid; idx < 72 * 8; idx += 512) {
        const int row = idx >> 3, slot = idx & 7;
        const int f = f0 - 4 + row;
        frag_ab vh = {0,0,0,0,0,0,0,0}, vl = {0,0,0,0,0,0,0,0};
        if (f >= 0 && f < FF) {
            const long off = ((long)(b * FF + f)) * CC + slot * 8;
            vh = *reinterpret_cast<const frag_ab*>(hinh + off);
            vl = *reinterpret_cast<const frag_ab*>(hinl + off);
        }
        const int a = row * 128 + ((slot ^ (row & 7)) << 4);
        *reinterpret_cast<frag_ab*>(&hbyh[a]) = vh;
        *reinterpret_cast<frag_ab*>(&hbyl[a]) = vl;
    }
    // ---- stage z tile [fl][kz<9], split hi/lo on the fly
    if (tid < 256) {
        const int fl = tid >> 2, slot = tid & 3;
        const float* zr = z + ((long)b * TT + t) * FF;
        short vh[8], vl[8];
        #pragma unroll
        for (int j = 0; j < 8; ++j) {
            const int kz = slot * 8 + j;
            const int f = f0 + fl - 4 + kz;
            const float val = (kz < 9 && f >= 0 && f < FF) ? zr[f] : 0.0f;
            split2(val, &vh[j], &vl[j]);
        }
        const int a = fl * 64 + ((slot ^ (fl & 3)) << 4);
        *reinterpret_cast<frag_ab*>(&zbyh[a]) = *reinterpret_cast<frag_ab*>(vh);
        *reinterpret_cast<frag_ab*>(&zbyl[a]) = *reinterpret_cast<frag_ab*>(vl);
    }
    __syncthreads();

    const int rA = lane & 15;     // A row within tile / B col within tile
    const int sA = lane >> 4;     // 0..3 : k-subslot

    f32x4 acc[4][2];
    #pragma unroll
    for (int gtI = 0; gtI < 2; ++gtI) {
        const float bv = bias[w * 32 + gtI * 16 + rA];
        #pragma unroll
        for (int Mt = 0; Mt < 4; ++Mt) acc[Mt][gtI] = (f32x4){bv, bv, bv, bv};
    }

    // ---- main loop: 9 taps x 2 cin-halves; 3-product bf16 (hi*hi + hi*lo + lo*hi)
    for (int k = 0; k < 9; ++k) {
        #pragma unroll
        for (int kk = 0; kk < 2; ++kk) {
            frag_ab bh[2], bl[2];
            #pragma unroll
            for (int gtI = 0; gtI < 2; ++gtI) {
                const long boff = ((long)(k * GG + w * 32 + gtI * 16 + rA)) * CC + kk * 32 + sA * 8;
                bh[gtI] = *reinterpret_cast<const frag_ab*>(WhTh + boff);
                bl[gtI] = *reinterpret_cast<const frag_ab*>(WhTl + boff);
            }
            frag_ab ah[4], al[4];
            #pragma unroll
            for (int Mt = 0; Mt < 4; ++Mt) {
                const int r = Mt * 16 + rA + k;
                const int s = kk * 4 + sA;
                const int a = r * 128 + ((s ^ (r & 7)) << 4);
                ah[Mt] = *reinterpret_cast<const frag_ab*>(&hbyh[a]);
                al[Mt] = *reinterpret_cast<const frag_ab*>(&hbyl[a]);
            }
            #pragma unroll
            for (int Mt = 0; Mt < 4; ++Mt)
                #pragma unroll
                for (int gtI = 0; gtI < 2; ++gtI) {
                    acc[Mt][gtI] = __builtin_amdgcn_mfma_f32_16x16x32_bf16(ah[Mt], bh[gtI], acc[Mt][gtI], 0, 0, 0);
                    acc[Mt][gtI] = __builtin_amdgcn_mfma_f32_16x16x32_bf16(ah[Mt], bl[gtI], acc[Mt][gtI], 0, 0, 0);
                    acc[Mt][gtI] = __builtin_amdgcn_mfma_f32_16x16x32_bf16(al[Mt], bh[gtI], acc[Mt][gtI], 0, 0, 0);
                }
        }
    }
    // ---- z tap (3-product as well)
    {
        frag_ab bh[2], bl[2];
        #pragma unroll
        for (int gtI = 0; gtI < 2; ++gtI) {
            const long boff = ((long)(w * 32 + gtI * 16 + rA)) * 32 + sA * 8;
            bh[gtI] = *reinterpret_cast<const frag_ab*>(WxTh + boff);
            bl[gtI] = *reinterpret_cast<const frag_ab*>(WxTl + boff);
        }
        frag_ab ah[4], al[4];
        #pragma unroll
        for (int Mt = 0; Mt < 4; ++Mt) {
            const int r = Mt * 16 + rA;
            const int a = r * 64 + ((sA ^ (r & 3)) << 4);
            ah[Mt] = *reinterpret_cast<const frag_ab*>(&zbyh[a]);
            al[Mt] = *reinterpret_cast<const frag_ab*>(&zbyl[a]);
        }
        #pragma unroll
        for (int Mt = 0; Mt < 4; ++Mt)
            #pragma unroll
            for (int gtI = 0; gtI < 2; ++gtI) {
                acc[Mt][gtI] = __builtin_amdgcn_mfma_f32_16x16x32_bf16(ah[Mt], bh[gtI], acc[Mt][gtI], 0, 0, 0);
                acc[Mt][gtI] = __builtin_amdgcn_mfma_f32_16x16x32_bf16(ah[Mt], bl[gtI], acc[Mt][gtI], 0, 0, 0);
                acc[Mt][gtI] = __builtin_amdgcn_mfma_f32_16x16x32_bf16(al[Mt], bh[gtI], acc[Mt][gtI], 0, 0, 0);
            }
    }

    // ---- scatter gates to LDS (C-layout: col=lane&15, row=sA*4+r)
    #pragma unroll
    for (int Mt = 0; Mt < 4; ++Mt)
        #pragma unroll
        for (int gtI = 0; gtI < 2; ++gtI) {
            const int g = w * 32 + gtI * 16 + rA;
            float* gp = &gbuf[(Mt * 16 + sA * 4) * GST + g];
            gp[0]       = acc[Mt][gtI][0];
            gp[GST]     = acc[Mt][gtI][1];
            gp[2 * GST] = acc[Mt][gtI][2];
            gp[3 * GST] = acc[Mt][gtI][3];
        }
    __syncthreads();

    // ---- LSTM cell update: thread -> (fl = tid>>3, 8 channels)
    const int fl = tid >> 3;
    const int ch0 = (tid & 7) * 8;
    const float* gp = &gbuf[fl * GST];
    const long cix = ((long)(b * FF + f0 + fl)) * CC + ch0;

    float hsum = 0.0f;
    float hv[8], cv[8];
    const float4 c01 = *reinterpret_cast<const float4*>(&c_in[cix]);
    const float4 c23 = *reinterpret_cast<const float4*>(&c_in[cix + 4]);
    const float cold[8] = {c01.x, c01.y, c01.z, c01.w, c23.x, c23.y, c23.z, c23.w};
    #pragma unroll
    for (int j = 0; j < 8; ++j) {
        const float gi = gp[ch0 + j];
        const float gj = gp[64 + ch0 + j];
        const float gf = gp[128 + ch0 + j];
        const float go = gp[192 + ch0 + j];
        const float cnew = cold[j] * sigmoidf_(gf + 1.0f) + sigmoidf_(gi) * tanhf(gj);
        const float hnew = tanhf(cnew) * sigmoidf_(go);
        cv[j] = cnew;
        hv[j] = hnew;
        hsum += hnew;
    }
    *reinterpret_cast<float4*>(&c_out[cix])     = make_float4(cv[0], cv[1], cv[2], cv[3]);
    *reinterpret_cast<float4*>(&c_out[cix + 4]) = make_float4(cv[4], cv[5], cv[6], cv[7]);
    short hh[8], hl[8];
    #pragma unroll
    for (int j = 0; j < 8; ++j) split2(hv[j], &hh[j], &hl[j]);
    *reinterpret_cast<frag_ab*>(&houth[cix]) = *reinterpret_cast<frag_ab*>(hh);
    *reinterpret_cast<frag_ab*>(&houtl[cix]) = *reinterpret_cast<frag_ab*>(hl);

    hsum += __shfl_xor(hsum, 1);
    hsum += __shfl_xor(hsum, 2);
    hsum += __shfl_xor(hsum, 4);
    if ((tid & 7) == 0)
        out[(long)b * (TT * FF) + t * FF + f0 + fl] = tanhf(hsum * (1.0f / 64.0f));
}

extern "C" void kernel_launch(void* const* d_in, const int* in_sizes, int n_in,
                              void* d_out, int out_size, void* d_ws, size_t ws_size,
                              hipStream_t stream) {
    const float* z    = (const float*)d_in[0];
    const float* h0   = (const float*)d_in[1];
    const float* c0   = (const float*)d_in[2];
    const float* Wx   = (const float*)d_in[3];
    const float* Wh   = (const float*)d_in[4];
    const float* bias = (const float*)d_in[5];
    float* out = (float*)d_out;

    const int SE = BB * FF * CC;        // 1,048,576
    short* hAh = (short*)d_ws;
    short* hAl = hAh + SE;
    short* hBh = hAl + SE;
    short* hBl = hBh + SE;
    float* cW  = (float*)(hBl + SE);
    short* WhTh = (short*)(cW + SE);
    short* WhTl = WhTh + 9 * GG * CC;
    short* WxTh = WhTl + 9 * GG * CC;
    short* WxTl = WxTh + GG * 32;

    prep_kernel<<<(SE + 255) / 256, 256, 0, stream>>>(Wh, Wx, h0, WhTh, WhTl,
                                                      WxTh, WxTl, hAh, hAl);

    dim3 grid(BB, FF / 64);  // 256 blocks
    for (int t = 0; t < TT; ++t) {
        const short* hih = (t & 1) ? hBh : hAh;
        const short* hil = (t & 1) ? hBl : hAl;
        short* hoh = (t & 1) ? hAh : hBh;
        short* hol = (t & 1) ? hAl : hBl;
        const float* cin = (t == 0) ? c0 : cW;
        convlstm_step<<<grid, 512, 0, stream>>>(z, hih, hil, cin,
                                                WhTh, WhTl, WxTh, WxTl, bias,
                                                hoh, hol, cW, out, t);
    }
}